// Round 4
// baseline (579.814 us; speedup 1.0000x reference)
//
#include <hip/hip_runtime.h>

#define BB 128
#define TT 512
#define CC 128

typedef short short8 __attribute__((ext_vector_type(8)));
typedef float f32x4  __attribute__((ext_vector_type(4)));

__device__ __forceinline__ unsigned pk_trunc(float a, float b) {
    // lo16 = trunc-bf16(a), hi16 = trunc-bf16(b); single v_perm
    return __builtin_amdgcn_perm(__float_as_uint(a), __float_as_uint(b), 0x03020706u);
}
__device__ __forceinline__ unsigned short f2bf(float f) {   // RNE (A setup only)
    unsigned u = __float_as_uint(f);
    u += 0x7fffu + ((u >> 16) & 1u);
    return (unsigned short)(u >> 16);
}
__device__ __forceinline__ float lo16f(unsigned u) { return __uint_as_float(u << 16); }
__device__ __forceinline__ float hi16f(unsigned u) { return __uint_as_float(u & 0xffff0000u); }

#define MFMA16(A, B, C) __builtin_amdgcn_mfma_f32_16x16x32_bf16((A), (B), (C), 0, 0, 0)

// ---------------------------------------------------------------------------
// One fused kernel, 256 threads per block.
// Blocks 0..7  : scan group g — SINGLE register-resident wave (waves 1..3 exit).
//                R0-verified sigma-permuted A layout: output channels per lane
//                == next step's B-frag channels (state stays in ps[16] regs —
//                no LDS, no barriers). E self-loaded as 8 float4/lane at the
//                sigma offsets 32(nt&3)+8q+4(nt>>2), depth-2 prefetch; exp on
//                TRANS pipe under the 32-MFMA shadow. Step cost ~= MFMA issue.
// Blocks 8..135: real-path score, 4 waves x 128 rows; atomicAdd(-score).
// R2/R3 lessons: LDS-exchange family floor ~750 cyc/step; co-located chains
// sum, not overlap. Single-wave reg-resident removes the exchange term.
// ---------------------------------------------------------------------------
__global__ __launch_bounds__(256, 1) void crf_all(
    const float* __restrict__ y_true, const float* __restrict__ y_pred,
    const float* __restrict__ mask, const float* __restrict__ trans,
    float* __restrict__ out)
{
    const int tid  = threadIdx.x;
    const int lane = tid & 63;
    const int w    = tid >> 6;

    if (blockIdx.x >= 8) {
        // ===================== real path (verified core, 4x128) =============
        const int rb  = blockIdx.x - 8;
        const int ts  = w * 128;
        const int te  = min(ts + 128, TT - 1);
        const float* yt_b = y_true + (size_t)rb * TT * CC;
        const float* yp_b = y_pred + (size_t)rb * TT * CC;
        const float* m_b  = mask + (size_t)rb * TT;

        float em = 0.f, tr = 0.f;
        int lprev = 0; float mprev = 0.f;
        const float* ytr = yt_b + ts * CC;
        const float* ypr = yp_b + ts * CC;
        float cyt0 = ytr[lane], cyt1 = ytr[lane + 64];
        float cyp0 = ypr[lane], cyp1 = ypr[lane + 64];
        float cm = m_b[ts];
        for (int t = ts; t <= te; ++t) {
            float nyt0 = 0.f, nyt1 = 0.f, nyp0 = 0.f, nyp1 = 0.f, nm = 0.f;
            if (t < te) {
                const float* ytn = yt_b + (t + 1) * CC;
                const float* ypn = yp_b + (t + 1) * CC;
                nyt0 = ytn[lane]; nyt1 = ytn[lane + 64];
                nyp0 = ypn[lane]; nyp1 = ypn[lane + 64];
                nm = m_b[t + 1];
            }
            unsigned long long b0 = __ballot(cyt0 > 0.5f);
            unsigned long long b1 = __ballot(cyt1 > 0.5f);
            int l = b0 ? (__ffsll(b0) - 1) : (64 + __ffsll(b1) - 1);
            float v0 = __shfl(cyp0, l & 63);
            float v1 = __shfl(cyp1, l & 63);
            float v  = (l < 64) ? v0 : v1;
            if (lane == 0) {
                if (t < ts + 128) em += cm * cm * v;
                if (t > ts)       tr += mprev * cm * trans[lprev * CC + l];
            }
            lprev = l; mprev = cm;
            cyt0 = nyt0; cyt1 = nyt1; cyp0 = nyp0; cyp1 = nyp1; cm = nm;
        }
        if (lane == 0) atomicAdd(&out[rb], -(em + tr));
        return;
    }

    // ========================== scan blocks ==========================
    if (w != 0) return;                      // single-wave chain; free the SIMDs

    const int bq = lane & 15;
    const int q  = lane >> 4;
    const int g  = blockIdx.x;
    const float* yb   = y_pred + (size_t)(g * 16 + bq) * TT * CC;
    const float* mrow = mask + (size_t)(g * 16 + bq) * TT;

    // sigma-permuted E offsets: float4 i covers channels 32(i&3)+8q+4(i>>2)+{0..3}
    int offc[8];
    #pragma unroll
    for (int i = 0; i < 8; ++i) offc[i] = 32 * (i & 3) + 8 * q + 4 * (i >> 2);

    // A-frags with row-perm sigma (R0-verified): output layout == B-frag layout.
    short8 Af[8][4];
    #pragma unroll
    for (int nt = 0; nt < 8; ++nt) {
        const int j = 32 * (nt & 3) + 8 * (bq >> 2) + 4 * (nt >> 2) + (bq & 3);
        #pragma unroll
        for (int kt = 0; kt < 4; ++kt) {
            #pragma unroll
            for (int e = 0; e < 8; ++e)
                Af[nt][kt][e] = (short)f2bf(__expf(trans[(kt * 32 + q * 8 + e) * CC + j]));
        }
    }

    // t=0 init: ps[4kt+j] covers channels 32kt+8q+{2j,2j+1}.
    unsigned ps[16];
    {
        const float m0 = mrow[0];
        #pragma unroll
        for (int kt = 0; kt < 4; ++kt) {
            float4 g0 = *(const float4*)(yb + offc[kt]);        // e0..e3
            float4 g1 = *(const float4*)(yb + offc[4 + kt]);    // e4..e7
            ps[4 * kt + 0] = pk_trunc(__expf(g0.x * m0), __expf(g0.y * m0));
            ps[4 * kt + 1] = pk_trunc(__expf(g0.z * m0), __expf(g0.w * m0));
            ps[4 * kt + 2] = pk_trunc(__expf(g1.x * m0), __expf(g1.y * m0));
            ps[4 * kt + 3] = pk_trunc(__expf(g1.z * m0), __expf(g1.w * m0));
        }
    }

    // depth-2 E prefetch (named slots — static register indexing, rule #20)
    float4 pfA[8], pfB[8]; float pmA, pmB;
    #pragma unroll
    for (int i = 0; i < 8; ++i) pfA[i] = *(const float4*)(yb + 1 * CC + offc[i]);
    pmA = mrow[1];
    #pragma unroll
    for (int i = 0; i < 8; ++i) pfB[i] = *(const float4*)(yb + 2 * CC + offc[i]);
    pmB = mrow[2];

    float lacc = 0.f, pend = 1.f;

    // One scan step, fully in registers.
    // RN at t%4==0: pend=1/state[0], lacc+=log. AP at t%4==1: apply pend.
    auto dostep = [&](const int t, float4 (&pf)[8], float& pm) {
        const float mm = pf[0].x * 0.f + pm;    // (plain pm; keep simple)
        // E exp early — TRANS pipe fills MFMA issue gaps.
        float e[8][4];
        #pragma unroll
        for (int i = 0; i < 8; ++i) {
            e[i][0] = __expf(pf[i].x * mm); e[i][1] = __expf(pf[i].y * mm);
            e[i][2] = __expf(pf[i].z * mm); e[i][3] = __expf(pf[i].w * mm);
        }
        // prefetch t+2 into this slot (after pf consumed into e)
        const int tn = t + 2;
        if (tn < TT) {
            const float* r = yb + (size_t)tn * CC;
            #pragma unroll
            for (int i = 0; i < 8; ++i) pf[i] = *(const float4*)(r + offc[i]);
            pm = mrow[tn];
        }
        short8 Bf[4];
        #pragma unroll
        for (int kt = 0; kt < 4; ++kt) {
            union { unsigned u[4]; short8 s; } bu;
            bu.u[0] = ps[4 * kt + 0]; bu.u[1] = ps[4 * kt + 1];
            bu.u[2] = ps[4 * kt + 2]; bu.u[3] = ps[4 * kt + 3];
            Bf[kt] = bu.s;
        }
        f32x4 acc[8];
        #pragma unroll
        for (int nt = 0; nt < 8; ++nt) { f32x4 z = {0.f,0.f,0.f,0.f}; acc[nt] = z; }
        #pragma unroll
        for (int kt = 0; kt < 4; ++kt)
            #pragma unroll
            for (int nt = 0; nt < 8; ++nt)
                acc[nt] = MFMA16(Af[nt][kt], Bf[kt], acc[nt]);
        const bool ap = (t & 3) == 1;
        float val[8][4];
        #pragma unroll
        for (int nt = 0; nt < 8; ++nt) {
            val[nt][0] = acc[nt][0] * e[nt][0]; val[nt][1] = acc[nt][1] * e[nt][1];
            val[nt][2] = acc[nt][2] * e[nt][2]; val[nt][3] = acc[nt][3] * e[nt][3];
            if (ap) {
                val[nt][0] *= pend; val[nt][1] *= pend;
                val[nt][2] *= pend; val[nt][3] *= pend;
            }
        }
        unsigned nps[16];
        #pragma unroll
        for (int nt = 0; nt < 8; ++nt) {
            const int kt = nt & 3, hh = nt >> 2;
            nps[kt * 4 + 2 * hh + 0] = pk_trunc(val[nt][0], val[nt][1]);
            nps[kt * 4 + 2 * hh + 1] = pk_trunc(val[nt][2], val[nt][3]);
        }
        if (__ballot(mm <= 0.f)) {              // rare keep-old (never at runtime)
            const float pe = ap ? pend : 1.f;
            #pragma unroll
            for (int p2 = 0; p2 < 16; ++p2) {
                unsigned kept = pk_trunc(lo16f(ps[p2]) * pe, hi16f(ps[p2]) * pe);
                nps[p2] = (mm <= 0.f) ? kept : nps[p2];
            }
        }
        #pragma unroll
        for (int p2 = 0; p2 < 16; ++p2) ps[p2] = nps[p2];
        if (ap) pend = 1.f;
        if ((t & 3) == 0) {                     // RN
            float s2 = lo16f(ps[0]);
            float bc = __shfl(s2, bq, 64);      // channel 0 lives at q=0 lanes
            pend = __builtin_amdgcn_rcpf(bc);
            lacc += __logf(bc);
        }
    };

    // steps 1..510 (odd -> slot A, even -> slot B)
    for (int t = 1; t <= 509; t += 2) {
        dostep(t,     pfA, pmA);
        dostep(t + 1, pfB, pmB);
    }

    // -------- step 511: final weighted sum (slot A; pend == 1, 511%4==3) ----
    {
        const float mm = pmA;
        float e[8][4];
        #pragma unroll
        for (int i = 0; i < 8; ++i) {
            e[i][0] = __expf(pfA[i].x * mm); e[i][1] = __expf(pfA[i].y * mm);
            e[i][2] = __expf(pfA[i].z * mm); e[i][3] = __expf(pfA[i].w * mm);
        }
        short8 Bf[4];
        #pragma unroll
        for (int kt = 0; kt < 4; ++kt) {
            union { unsigned u[4]; short8 s; } bu;
            bu.u[0] = ps[4 * kt + 0]; bu.u[1] = ps[4 * kt + 1];
            bu.u[2] = ps[4 * kt + 2]; bu.u[3] = ps[4 * kt + 3];
            Bf[kt] = bu.s;
        }
        f32x4 acc[8];
        #pragma unroll
        for (int nt = 0; nt < 8; ++nt) { f32x4 z = {0.f,0.f,0.f,0.f}; acc[nt] = z; }
        #pragma unroll
        for (int kt = 0; kt < 4; ++kt)
            #pragma unroll
            for (int nt = 0; nt < 8; ++nt)
                acc[nt] = MFMA16(Af[nt][kt], Bf[kt], acc[nt]);
        float ssum = 0.f;
        #pragma unroll
        for (int nt = 0; nt < 8; ++nt)
            ssum += acc[nt][0] * e[nt][0] + acc[nt][1] * e[nt][1]
                  + acc[nt][2] * e[nt][2] + acc[nt][3] * e[nt][3];
        if (__ballot(mm <= 0.f)) {
            float os = 0.f;
            #pragma unroll
            for (int p2 = 0; p2 < 16; ++p2) os += lo16f(ps[p2]) + hi16f(ps[p2]);
            ssum = (mm <= 0.f) ? os : ssum;
        }
        ssum += __shfl_xor(ssum, 16, 64);
        ssum += __shfl_xor(ssum, 32, 64);
        if (lane < 16) atomicAdd(&out[g * 16 + lane], __logf(ssum) + lacc);
    }
}

// ---------------------------------------------------------------------------
extern "C" void kernel_launch(void* const* d_in, const int* in_sizes, int n_in,
                              void* d_out, int out_size, void* d_ws, size_t ws_size,
                              hipStream_t stream) {
    (void)in_sizes; (void)n_in; (void)out_size; (void)d_ws; (void)ws_size;
    const float* y_true = (const float*)d_in[0];
    const float* y_pred = (const float*)d_in[1];
    const float* mask   = (const float*)d_in[2];
    const float* trans  = (const float*)d_in[3];
    float* out = (float*)d_out;

    hipMemsetAsync(out, 0, BB * sizeof(float), stream);
    crf_all<<<dim3(8 + BB), 256, 0, stream>>>(y_true, y_pred, mask, trans, out);
}